// Round 7
// baseline (269.769 us; speedup 1.0000x reference)
//
#include <hip/hip_runtime.h>

typedef float f32x4 __attribute__((ext_vector_type(4)));
typedef short s16x8 __attribute__((ext_vector_type(8)));
typedef unsigned int u32x4 __attribute__((ext_vector_type(4)));
typedef unsigned short u16;
typedef unsigned int u32;

#define QK_SCALE 0.17677669529663687f  // 32^-0.5

__device__ __forceinline__ u16 f2bf(float f) {
    unsigned u = __builtin_bit_cast(unsigned, f);
    u = (u + 0x7fffu + ((u >> 16) & 1u)) >> 16;
    return (u16)u;
}
__device__ __forceinline__ u32 pk2(float lo, float hi) {
    return (u32)f2bf(lo) | ((u32)f2bf(hi) << 16);
}

// C-frag(pair) -> operand-frag conversion:
// dst lane (c,g) elem e needs M[t=c][u=8g+e]; src lane (c, 2(g&1)+(e>>2)),
// utile=g>>1, j=e&3.  r0/r1 = packed (j0,j1)/(j2,j3) words per utile.
__device__ __forceinline__ s16x8 frag4(u32 r0u0, u32 r1u0, u32 r0u1, u32 r1u1,
                                       int aA, int aB, bool lo) {
    u32x4 w;
    u32 a, bq;
    a  = (u32)__builtin_amdgcn_ds_bpermute(aA, (int)r0u0);
    bq = (u32)__builtin_amdgcn_ds_bpermute(aA, (int)r0u1);
    w[0] = lo ? a : bq;
    a  = (u32)__builtin_amdgcn_ds_bpermute(aA, (int)r1u0);
    bq = (u32)__builtin_amdgcn_ds_bpermute(aA, (int)r1u1);
    w[1] = lo ? a : bq;
    a  = (u32)__builtin_amdgcn_ds_bpermute(aB, (int)r0u0);
    bq = (u32)__builtin_amdgcn_ds_bpermute(aB, (int)r0u1);
    w[2] = lo ? a : bq;
    a  = (u32)__builtin_amdgcn_ds_bpermute(aB, (int)r1u0);
    bq = (u32)__builtin_amdgcn_ds_bpermute(aB, (int)r1u1);
    w[3] = lo ? a : bq;
    return __builtin_bit_cast(s16x8, w);
}

// ---- workspace byte offsets ----
#define WS_PROJW 393216
#define WS_BIASC 524288
#define WS_MASKC 655360
#define WS_VBIAS 1703936

__global__ void prep(const float* __restrict__ qkv_w, const float* __restrict__ proj_w,
                     const float* __restrict__ bias_table, const int* __restrict__ rel_index,
                     const float* __restrict__ mask, const float* __restrict__ qkv_b,
                     u16* __restrict__ wqkvC2, u16* __restrict__ projwC,
                     float* __restrict__ biasC2, float* __restrict__ maskC2,
                     float* __restrict__ vbias) {
    int i = blockIdx.x * 256 + threadIdx.x;
    if (i < 196608) {                       // qkv weights as A-frags of W·X^T
        int e = i & 7, lane = (i >> 3) & 63, ks = (i >> 9) & 7, dt = (i >> 12) & 1;
        int i2 = i >> 13, t = i2 % 3, h = i2 / 3;
        int c = lane & 15, g = lane >> 4;
        wqkvC2[i] = f2bf(qkv_w[(t * 256 + h * 32 + dt * 16 + c) * 256 + ks * 32 + g * 8 + e]);
    }
    if (i < 65536) {                        // proj weights -> fragment order
        int e = i & 7, lane = (i >> 3) & 63, ks = (i >> 9) & 7, nt = (i >> 12) & 15;
        int c = lane & 15, g = lane >> 4;
        projwC[i] = f2bf(proj_w[(nt * 16 + c) * 256 + ks * 32 + g * 8 + e]);
    }
    if (i < 32768) {                        // rel-pos bias in St C-frag order
        int j = i & 3, lane = (i >> 2) & 63, mtK = (i >> 8) & 3, ntQ = (i >> 10) & 3, h = i >> 12;
        int c = lane & 15, g = lane >> 4;
        int q = ntQ * 16 + c, k = mtK * 16 + g * 4 + j;
        float v;
        if (k < 49) v = (q < 49) ? bias_table[rel_index[q * 49 + k] * 8 + h] : 0.f;
        else        v = -1e30f;
        biasC2[i] = v;
    }
    if (i < 262144) {                       // shift mask in St C-frag order
        int j = i & 3, lane = (i >> 2) & 63, mtK = (i >> 8) & 3, ntQ = (i >> 10) & 3, wi = i >> 12;
        int c = lane & 15, g = lane >> 4;
        int q = ntQ * 16 + c, k = mtK * 16 + g * 4 + j;
        maskC2[i] = (q < 49 && k < 49) ? mask[wi * 2401 + q * 49 + k] : 0.f;
    }
    if (i < 12288) {                        // qkv bias in C-frag row order
        int j = i & 3, lane = (i >> 2) & 63, dt = (i >> 8) & 1;
        int i2 = i >> 9, t = i2 % 3, h = i2 / 3;
        int g = lane >> 4;
        vbias[i] = qkv_b[t * 256 + h * 32 + dt * 16 + g * 4 + j];
    }
}

// ---- LDS (u16 offsets), total 31368 u16 = 62,736 B -> 2 blocks/CU, 16 waves/CU ----
// XS  : [0, 12936)  49 rows x 264  (x window, bf16)
// VT  : 12936 + wv*2304, [d32][tok72-pad] per wave (8 waves)
// OUTS: [0, 12936)  overlaps XS after barrier
__global__ __launch_bounds__(512, 4)
void swin_attn(const float* __restrict__ x,
               const float* __restrict__ proj_b,
               const u16* __restrict__ wqkvC2,
               const u16* __restrict__ projwC,
               const float* __restrict__ biasC2,
               const float* __restrict__ maskC2,
               const float* __restrict__ vbias,
               float* __restrict__ out) {
    __shared__ __align__(16) u16 sm[31368];
    const int b = blockIdx.x, tid = threadIdx.x;
    const int wv = tid >> 6, lane = tid & 63, g = lane >> 4, c = lane & 15;
    const int wi = b & 63;
    const int h = wv;                     // one head per wave
    const int VTb = 12936 + wv * 2304;
    const float* xw = x + (size_t)b * 12544;

    // stage x window (bf16), rows 0..48
    for (int i = tid; i < 49 * 64; i += 512) {
        int row = i >> 6, q4 = i & 63;
        float4 v = ((const float4*)xw)[i];
        ushort4 s;
        s.x = f2bf(v.x); s.y = f2bf(v.y); s.z = f2bf(v.z); s.w = f2bf(v.w);
        *(ushort4*)&sm[row * 264 + q4 * 4] = s;
    }
    __syncthreads();

    const int addrA = ((lane & 15) + ((lane & 16) << 1)) << 2;  // src lane c+32*(g&1)
    const int addrB = addrA + 64;                               // +16 lanes
    const bool lo = lane < 32;                                  // utile = g>>1
    const s16x8 zfrag = {0, 0, 0, 0, 0, 0, 0, 0};

    // ---- QKV as W·X^T, split by dt (16-col halves) to bound VGPR pressure ----
    u32 qp[4][2][2], kp[4][2][2];
#pragma unroll
    for (int dt = 0; dt < 2; ++dt) {
        f32x4 acc[3][4];
#pragma unroll
        for (int t = 0; t < 3; ++t)
#pragma unroll
            for (int tt = 0; tt < 4; ++tt) acc[t][tt] = f32x4{0.f, 0.f, 0.f, 0.f};
#pragma unroll
        for (int ks = 0; ks < 8; ++ks) {
            s16x8 Xf[4];
#pragma unroll
            for (int tt = 0; tt < 4; ++tt)
                Xf[tt] = *(const s16x8*)&sm[(tt * 16 + c) * 264 + ks * 32 + g * 8];
            if (c > 0) Xf[3] = zfrag;      // tokens 49..63 zero
#pragma unroll
            for (int t = 0; t < 3; ++t) {
                s16x8 Wf = *(const s16x8*)&wqkvC2[(((((h * 3 + t) * 2 + dt) * 8 + ks) * 64) + lane) * 8];
#pragma unroll
                for (int tt = 0; tt < 4; ++tt)
                    acc[t][tt] = __builtin_amdgcn_mfma_f32_16x16x32_bf16(Wf, Xf[tt], acc[t][tt], 0, 0, 0);
            }
        }
        // bias; pack Qt/Kt to regs; Vt -> VT LDS
#pragma unroll
        for (int t = 0; t < 3; ++t) {
            f32x4 bv = *(const f32x4*)&vbias[(((h * 3 + t) * 2 + dt) * 64 + lane) * 4];
#pragma unroll
            for (int tt = 0; tt < 4; ++tt) {
                float v0 = acc[t][tt][0] + bv[0];
                float v1 = acc[t][tt][1] + bv[1];
                float v2 = acc[t][tt][2] + bv[2];
                float v3 = acc[t][tt][3] + bv[3];
                if (t == 0) {
                    qp[tt][dt][0] = pk2(v0 * QK_SCALE, v1 * QK_SCALE);
                    qp[tt][dt][1] = pk2(v2 * QK_SCALE, v3 * QK_SCALE);
                } else if (t == 1) {
                    kp[tt][dt][0] = pk2(v0, v1);
                    kp[tt][dt][1] = pk2(v2, v3);
                } else {
                    sm[VTb + (dt * 16 + g * 4 + 0) * 72 + tt * 16 + c] = f2bf(v0);
                    sm[VTb + (dt * 16 + g * 4 + 1) * 72 + tt * 16 + c] = f2bf(v1);
                    sm[VTb + (dt * 16 + g * 4 + 2) * 72 + tt * 16 + c] = f2bf(v2);
                    sm[VTb + (dt * 16 + g * 4 + 3) * 72 + tt * 16 + c] = f2bf(v3);
                }
            }
        }
    }

    // ---- operand frags for St = K·Q^T (both lane&15 = token) ----
    s16x8 Qf[4], Kf[4];
#pragma unroll
    for (int nt = 0; nt < 4; ++nt)
        Qf[nt] = frag4(qp[nt][0][0], qp[nt][0][1], qp[nt][1][0], qp[nt][1][1], addrA, addrB, lo);
#pragma unroll
    for (int mt = 0; mt < 4; ++mt)
        Kf[mt] = frag4(kp[mt][0][0], kp[mt][0][1], kp[mt][1][0], kp[mt][1][1], addrA, addrB, lo);

    // ---- St (16 MFMA) + bias + mask, softmax (q = c, k' = mtK*16+g*4+j) ----
    f32x4 lv[4][4];
#pragma unroll
    for (int mtK = 0; mtK < 4; ++mtK)
#pragma unroll
        for (int ntQ = 0; ntQ < 4; ++ntQ) {
            f32x4 z = {0.f, 0.f, 0.f, 0.f};
            lv[mtK][ntQ] = __builtin_amdgcn_mfma_f32_16x16x32_bf16(Kf[mtK], Qf[ntQ], z, 0, 0, 0);
        }
    float mx[4] = {-1e30f, -1e30f, -1e30f, -1e30f};
#pragma unroll
    for (int ntQ = 0; ntQ < 4; ++ntQ)
#pragma unroll
        for (int mtK = 0; mtK < 4; ++mtK) {
            f32x4 bb = *(const f32x4*)&biasC2[((h * 16 + ntQ * 4 + mtK) * 64 + lane) * 4];
            f32x4 mm = *(const f32x4*)&maskC2[((wi * 16 + ntQ * 4 + mtK) * 64 + lane) * 4];
#pragma unroll
            for (int j = 0; j < 4; ++j) {
                float v = lv[mtK][ntQ][j] + bb[j] + mm[j];
                lv[mtK][ntQ][j] = v;
                mx[ntQ] = fmaxf(mx[ntQ], v);
            }
        }
#pragma unroll
    for (int ntQ = 0; ntQ < 4; ++ntQ) {
        float m = mx[ntQ];
        m = fmaxf(m, __shfl_xor(m, 16));
        m = fmaxf(m, __shfl_xor(m, 32));
        mx[ntQ] = m;
    }
    float sums[4] = {0.f, 0.f, 0.f, 0.f};
#pragma unroll
    for (int ntQ = 0; ntQ < 4; ++ntQ)
#pragma unroll
        for (int mtK = 0; mtK < 4; ++mtK)
#pragma unroll
            for (int j = 0; j < 4; ++j) {
                float e = __expf(lv[mtK][ntQ][j] - mx[ntQ]);
                lv[mtK][ntQ][j] = e;
                sums[ntQ] += e;
            }
#pragma unroll
    for (int ntQ = 0; ntQ < 4; ++ntQ) {
        float s = sums[ntQ];
        s += __shfl_xor(s, 16);
        s += __shfl_xor(s, 32);
        sums[ntQ] = 1.0f / s;
    }
    // normalized P packed (q = c, so inv-sum is lane-local)
    u32 pp[4][4][2];
#pragma unroll
    for (int mtK = 0; mtK < 4; ++mtK)
#pragma unroll
        for (int ntQ = 0; ntQ < 4; ++ntQ) {
            float is = sums[ntQ];
            pp[mtK][ntQ][0] = pk2(lv[mtK][ntQ][0] * is, lv[mtK][ntQ][1] * is);
            pp[mtK][ntQ][1] = pk2(lv[mtK][ntQ][2] * is, lv[mtK][ntQ][3] * is);
        }

    // ---- PV: A = P-frag (bpermute), B = VT from LDS ----
    u32 opk[4][2][2];
#pragma unroll
    for (int mtQ = 0; mtQ < 4; ++mtQ) {
        f32x4 o[2] = {{0.f, 0.f, 0.f, 0.f}, {0.f, 0.f, 0.f, 0.f}};
#pragma unroll
        for (int ks2 = 0; ks2 < 2; ++ks2) {
            s16x8 Pf = frag4(pp[2 * ks2][mtQ][0], pp[2 * ks2][mtQ][1],
                             pp[2 * ks2 + 1][mtQ][0], pp[2 * ks2 + 1][mtQ][1], addrA, addrB, lo);
#pragma unroll
            for (int ndt = 0; ndt < 2; ++ndt) {
                s16x8 Vf = *(const s16x8*)&sm[VTb + (ndt * 16 + c) * 72 + ks2 * 32 + g * 8];
                o[ndt] = __builtin_amdgcn_mfma_f32_16x16x32_bf16(Pf, Vf, o[ndt], 0, 0, 0);
            }
        }
#pragma unroll
        for (int ndt = 0; ndt < 2; ++ndt) {
            opk[mtQ][ndt][0] = pk2(o[ndt][0], o[ndt][1]);
            opk[mtQ][ndt][1] = pk2(o[ndt][2], o[ndt][3]);
        }
    }

    __syncthreads();   // all waves done with XS reads
    // stage head outputs into OUTS (overlaps XS); head h -> cols [h*32, h*32+32)
#pragma unroll
    for (int mt = 0; mt < 4; ++mt)
#pragma unroll
        for (int n2 = 0; n2 < 2; ++n2)
#pragma unroll
            for (int jj = 0; jj < 2; ++jj) {
                u32 w = opk[mt][n2][jj];
                int row = mt * 16 + g * 4 + jj * 2;
                int colb = h * 32 + n2 * 16 + c;
                if (row < 49)     sm[row * 264 + colb] = (u16)(w & 0xffffu);
                if (row + 1 < 49) sm[(row + 1) * 264 + colb] = (u16)(w >> 16);
            }
    __syncthreads();

    // ---- output projection: wave wv covers cols [wv*32, wv*32+32) ----
    f32x4 pacc[4][2];
#pragma unroll
    for (int mt = 0; mt < 4; ++mt)
#pragma unroll
        for (int n = 0; n < 2; ++n) pacc[mt][n] = f32x4{0.f, 0.f, 0.f, 0.f};
#pragma unroll
    for (int ks = 0; ks < 8; ++ks) {
        s16x8 ao[4];
#pragma unroll
        for (int mt = 0; mt < 4; ++mt) {
            int row = mt * 16 + c; row = row > 48 ? 48 : row;
            ao[mt] = *(const s16x8*)&sm[row * 264 + ks * 32 + g * 8];
        }
#pragma unroll
        for (int n = 0; n < 2; ++n) {
            s16x8 bp = *(const s16x8*)&projwC[(((wv * 2 + n) * 8 + ks) * 64 + lane) * 8];
#pragma unroll
            for (int mt = 0; mt < 4; ++mt)
                pacc[mt][n] = __builtin_amdgcn_mfma_f32_16x16x32_bf16(ao[mt], bp, pacc[mt][n], 0, 0, 0);
        }
    }
    float* ob = out + (size_t)b * 12544;
#pragma unroll
    for (int n = 0; n < 2; ++n) {
        int col = (wv * 2 + n) * 16 + c;
        float pb = proj_b[col];
#pragma unroll
        for (int mt = 0; mt < 4; ++mt)
#pragma unroll
            for (int j = 0; j < 4; ++j) {
                int row = mt * 16 + g * 4 + j;
                if (row < 49) ob[row * 256 + col] = pacc[mt][n][j] + pb;
            }
    }
}

extern "C" void kernel_launch(void* const* d_in, const int* in_sizes, int n_in,
                              void* d_out, int out_size, void* d_ws, size_t ws_size,
                              hipStream_t stream) {
    const float* x          = (const float*)d_in[0];
    const float* mask       = (const float*)d_in[1];
    const float* qkv_w      = (const float*)d_in[2];
    const float* qkv_b      = (const float*)d_in[3];
    const float* bias_table = (const float*)d_in[4];
    const float* proj_w     = (const float*)d_in[5];
    const float* proj_b     = (const float*)d_in[6];
    const int*   rel_index  = (const int*)d_in[7];

    u16*   wqkvC2 = (u16*)d_ws;
    u16*   projwC = (u16*)((char*)d_ws + WS_PROJW);
    float* biasC2 = (float*)((char*)d_ws + WS_BIASC);
    float* maskC2 = (float*)((char*)d_ws + WS_MASKC);
    float* vbias  = (float*)((char*)d_ws + WS_VBIAS);

    prep<<<1024, 256, 0, stream>>>(qkv_w, proj_w, bias_table, rel_index, mask, qkv_b,
                                   wqkvC2, projwC, biasC2, maskC2, vbias);
    swin_attn<<<2048, 512, 0, stream>>>(x, proj_b, wqkvC2, projwC, biasC2, maskC2, vbias,
                                        (float*)d_out);
}

// Round 8
// 160.458 us; speedup vs baseline: 1.6812x; 1.6812x over previous
//
#include <hip/hip_runtime.h>

typedef float f32x4 __attribute__((ext_vector_type(4)));
typedef short s16x8 __attribute__((ext_vector_type(8)));
typedef unsigned short u16;
typedef unsigned int u32;

#define QK_SCALE 0.17677669529663687f  // 32^-0.5

__device__ __forceinline__ u16 f2bf(float f) {
    unsigned u = __builtin_bit_cast(unsigned, f);
    u = (u + 0x7fffu + ((u >> 16) & 1u)) >> 16;
    return (u16)u;
}
__device__ __forceinline__ u32 pk2(float lo, float hi) {
    return (u32)f2bf(lo) | ((u32)f2bf(hi) << 16);
}

// ---- workspace byte offsets ----
// qkvwC : 196608 bf16 = 393216 B    [h8][t6][ks8][lane64][e8]
// projwC:  65536 bf16 = 131072 B    [nt16][ks8][lane64][e8]
// bmC   : 2097152 bf16 = 4194304 B  [wi64][h8][tile16][lane64][j4]  (bias+mask merged, k>=49 -> -1e30)
#define WS_PROJW 393216
#define WS_BMC   524288

__global__ void prep(const float* __restrict__ qkv_w, const float* __restrict__ proj_w,
                     const float* __restrict__ bias_table, const int* __restrict__ rel_index,
                     const float* __restrict__ mask,
                     u16* __restrict__ qkvwC, u16* __restrict__ projwC,
                     u16* __restrict__ bmC) {
    int i = blockIdx.x * 256 + threadIdx.x;
    if (i < 196608) {                       // qkv weights -> fragment order
        int e = i & 7, lane = (i >> 3) & 63, ks = (i >> 9) & 7, i2 = i >> 12;
        int t = i2 % 6, h = i2 / 6;
        int c = lane & 15, g = lane >> 4;
        int wrow = (t >> 1) * 256 + h * 32 + (t & 1) * 16 + c;
        qkvwC[i] = f2bf(qkv_w[wrow * 256 + ks * 32 + g * 8 + e]);
    }
    if (i < 65536) {                        // proj weights -> fragment order
        int e = i & 7, lane = (i >> 3) & 63, ks = (i >> 9) & 7, nt = (i >> 12) & 15;
        int c = lane & 15, g = lane >> 4;
        projwC[i] = f2bf(proj_w[(nt * 16 + c) * 256 + ks * 32 + g * 8 + e]);
    }
    {                                       // merged bias+mask, bf16, C-frag order
        int j = i & 3, lane = (i >> 2) & 63, tile = (i >> 8) & 15, h = (i >> 12) & 7, wi = i >> 15;
        int mt = tile >> 2, nt = tile & 3, g = lane >> 4, c = lane & 15;
        int q = mt * 16 + g * 4 + j, k = nt * 16 + c;
        float v;
        if (k < 49) v = (q < 49) ? bias_table[rel_index[q * 49 + k] * 8 + h]
                                   + mask[wi * 2401 + q * 49 + k]
                                 : 0.f;
        else        v = -1e30f;             // pad-column mask folded in
        bmC[i] = f2bf(v);
    }
}

// ---- LDS layout (ushort offsets), total 38416 ushorts = 76,832 B -> 2 blocks/CU ----
// XS   : 0,               stride 264, 50 rows (row 49 zeroed)
// wave scratch at PW = 13200 + wv*6304:
//   Q  : PW,        stride 40, 50 rows (2000)
//   K  : PW+2000,   stride 40, 50 rows (2000)
//   VT : PW+4000,   stride 72, 32 d-rows (2304)
//   P  : PW (overlaps dead Q+K), stride 72, 50 rows (3600 <= 4000)
// OUTS : 13200 (overlaps wave scratch after barrier), stride 264, 49 rows
__global__ __launch_bounds__(256, 2)
void swin_attn(const float* __restrict__ x,
               const float* __restrict__ qkv_b,
               const float* __restrict__ proj_b,
               const u16* __restrict__ qkvwC,
               const u16* __restrict__ projwC,
               const u16* __restrict__ bmC,
               float* __restrict__ out) {
    __shared__ __align__(16) u16 sm[38416];
    const int b = blockIdx.x, tid = threadIdx.x;
    const int wv = tid >> 6, lane = tid & 63, g = lane >> 4, c = lane & 15;
    const int wi = b & 63;
    const int PW = 13200 + wv * 6304;
    const float* xw = x + (size_t)b * 12544;

    // stage x window (bf16) rows 0..48, zero row 49
    for (int i = tid; i < 49 * 64; i += 256) {
        int row = i >> 6, q4 = i & 63;
        float4 v = ((const float4*)xw)[i];
        ushort4 s;
        s.x = f2bf(v.x); s.y = f2bf(v.y); s.z = f2bf(v.z); s.w = f2bf(v.w);
        *(ushort4*)&sm[row * 264 + q4 * 4] = s;
    }
    if (tid < 64) *(ushort4*)&sm[49 * 264 + tid * 4] = make_ushort4(0, 0, 0, 0);
    __syncthreads();

    float oreg[2][4][2][4];

#pragma unroll
    for (int hl = 0; hl < 2; ++hl) {
        const int hh = wv * 2 + hl;

        // ---- Phase B: QKV projection, double-buffered weight prefetch ----
        f32x4 acc[4][6];
#pragma unroll
        for (int mt = 0; mt < 4; ++mt)
#pragma unroll
            for (int t = 0; t < 6; ++t) acc[mt][t] = f32x4{0.f, 0.f, 0.f, 0.f};

        s16x8 wf[2][6];
#pragma unroll
        for (int t = 0; t < 6; ++t)
            wf[0][t] = *(const s16x8*)&qkvwC[(((hh * 6 + t) * 8 + 0) * 64 + lane) * 8];
#pragma unroll
        for (int ks = 0; ks < 8; ++ks) {
            if (ks < 7) {
#pragma unroll
                for (int t = 0; t < 6; ++t)
                    wf[(ks + 1) & 1][t] =
                        *(const s16x8*)&qkvwC[(((hh * 6 + t) * 8 + (ks + 1)) * 64 + lane) * 8];
            }
            s16x8 a[4];
#pragma unroll
            for (int mt = 0; mt < 4; ++mt) {
                int row = mt * 16 + c; row = row > 49 ? 49 : row;
                a[mt] = *(const s16x8*)&sm[row * 264 + ks * 32 + g * 8];
            }
#pragma unroll
            for (int t = 0; t < 6; ++t)
#pragma unroll
                for (int mt = 0; mt < 4; ++mt)
                    acc[mt][t] = __builtin_amdgcn_mfma_f32_16x16x32_bf16(a[mt], wf[ks & 1][t], acc[mt][t], 0, 0, 0);
        }
        // distribute to wave-private Q / K / V^T
#pragma unroll
        for (int t = 0; t < 6; ++t) {
            float bb = qkv_b[(t >> 1) * 256 + hh * 32 + (t & 1) * 16 + c];
#pragma unroll
            for (int mt = 0; mt < 4; ++mt)
#pragma unroll
                for (int j = 0; j < 4; ++j) {
                    int row = mt * 16 + g * 4 + j;
                    float v = acc[mt][t][j] + bb;
                    if (t < 2)      { if (row < 50) sm[PW + row * 40 + (t & 1) * 16 + c] = f2bf(v * QK_SCALE); }
                    else if (t < 4) { if (row < 50) sm[PW + 2000 + row * 40 + (t & 1) * 16 + c] = f2bf(v); }
                    else            { sm[PW + 4000 + ((t & 1) * 16 + c) * 72 + row] = f2bf(v); }
                }
        }

        // ---- Phase C: QK^T + merged bias/mask (bf16), wave-local softmax ----
        s16x8 aq[4], bk[4];
#pragma unroll
        for (int mt = 0; mt < 4; ++mt) {
            int row = mt * 16 + c; row = row > 49 ? 49 : row;
            aq[mt] = *(const s16x8*)&sm[PW + row * 40 + g * 8];
        }
#pragma unroll
        for (int nt = 0; nt < 4; ++nt) {
            int row = nt * 16 + c; row = row > 49 ? 49 : row;
            bk[nt] = *(const s16x8*)&sm[PW + 2000 + row * 40 + g * 8];
        }
        float lv[4][4][4], mx[4][4];
#pragma unroll
        for (int mt = 0; mt < 4; ++mt)
#pragma unroll
            for (int j = 0; j < 4; ++j) mx[mt][j] = -1e30f;
#pragma unroll
        for (int mt = 0; mt < 4; ++mt)
#pragma unroll
            for (int nt = 0; nt < 4; ++nt) {
                f32x4 z = {0.f, 0.f, 0.f, 0.f};
                f32x4 s4 = __builtin_amdgcn_mfma_f32_16x16x32_bf16(aq[mt], bk[nt], z, 0, 0, 0);
                const u16* bmp = &bmC[(((((wi * 8 + hh) * 16) + mt * 4 + nt) * 64 + lane) * 4)];
                u32 w0 = ((const u32*)bmp)[0];
                u32 w1 = ((const u32*)bmp)[1];
                float b0 = __builtin_bit_cast(float, w0 << 16);
                float b1 = __builtin_bit_cast(float, w0 & 0xffff0000u);
                float b2 = __builtin_bit_cast(float, w1 << 16);
                float b3 = __builtin_bit_cast(float, w1 & 0xffff0000u);
                float v0 = s4[0] + b0, v1 = s4[1] + b1, v2 = s4[2] + b2, v3 = s4[3] + b3;
                lv[mt][nt][0] = v0; lv[mt][nt][1] = v1;
                lv[mt][nt][2] = v2; lv[mt][nt][3] = v3;
                mx[mt][0] = fmaxf(mx[mt][0], v0);
                mx[mt][1] = fmaxf(mx[mt][1], v1);
                mx[mt][2] = fmaxf(mx[mt][2], v2);
                mx[mt][3] = fmaxf(mx[mt][3], v3);
            }
#pragma unroll
        for (int mt = 0; mt < 4; ++mt)
#pragma unroll
            for (int j = 0; j < 4; ++j) {
                float m = mx[mt][j];
                m = fmaxf(m, __shfl_xor(m, 1));
                m = fmaxf(m, __shfl_xor(m, 2));
                m = fmaxf(m, __shfl_xor(m, 4));
                m = fmaxf(m, __shfl_xor(m, 8));
                mx[mt][j] = m;
            }
        float sums[4][4];
#pragma unroll
        for (int mt = 0; mt < 4; ++mt)
#pragma unroll
            for (int j = 0; j < 4; ++j) sums[mt][j] = 0.f;
#pragma unroll
        for (int mt = 0; mt < 4; ++mt)
#pragma unroll
            for (int nt = 0; nt < 4; ++nt)
#pragma unroll
                for (int j = 0; j < 4; ++j) {
                    float e = __expf(lv[mt][nt][j] - mx[mt][j]);
                    lv[mt][nt][j] = e;
                    sums[mt][j] += e;
                }
#pragma unroll
        for (int mt = 0; mt < 4; ++mt)
#pragma unroll
            for (int j = 0; j < 4; ++j) {
                float s = sums[mt][j];
                s += __shfl_xor(s, 1);
                s += __shfl_xor(s, 2);
                s += __shfl_xor(s, 4);
                s += __shfl_xor(s, 8);
                sums[mt][j] = 1.0f / s;     // normalization deferred to PV output
            }
        // write unnormalized P (overlaps dead Q+K)
#pragma unroll
        for (int mt = 0; mt < 4; ++mt)
#pragma unroll
            for (int nt = 0; nt < 4; ++nt)
#pragma unroll
                for (int j = 0; j < 4; ++j) {
                    int row = mt * 16 + g * 4 + j;
                    if (row < 50) sm[PW + row * 72 + nt * 16 + c] = f2bf(lv[mt][nt][j]);
                }

        // ---- Phase D: PV ----
        f32x4 o[4][2];
#pragma unroll
        for (int mt = 0; mt < 4; ++mt)
#pragma unroll
            for (int n2 = 0; n2 < 2; ++n2) o[mt][n2] = f32x4{0.f, 0.f, 0.f, 0.f};
#pragma unroll
        for (int ks2 = 0; ks2 < 2; ++ks2) {
            s16x8 ap[4], bv2[2];
#pragma unroll
            for (int mt = 0; mt < 4; ++mt) {
                int row = mt * 16 + c; row = row > 49 ? 49 : row;
                ap[mt] = *(const s16x8*)&sm[PW + row * 72 + ks2 * 32 + g * 8];
            }
#pragma unroll
            for (int n2 = 0; n2 < 2; ++n2)
                bv2[n2] = *(const s16x8*)&sm[PW + 4000 + (n2 * 16 + c) * 72 + ks2 * 32 + g * 8];
#pragma unroll
            for (int mt = 0; mt < 4; ++mt)
#pragma unroll
                for (int n2 = 0; n2 < 2; ++n2)
                    o[mt][n2] = __builtin_amdgcn_mfma_f32_16x16x32_bf16(ap[mt], bv2[n2], o[mt][n2], 0, 0, 0);
        }
#pragma unroll
        for (int mt = 0; mt < 4; ++mt)
#pragma unroll
            for (int n2 = 0; n2 < 2; ++n2)
#pragma unroll
                for (int j = 0; j < 4; ++j)
                    oreg[hl][mt][n2][j] = o[mt][n2][j] * sums[mt][j];
    }

    __syncthreads();   // all waves done with private scratch
    // stage head outputs (bf16) into OUTS (overlaps wave scratch)
#pragma unroll
    for (int hl = 0; hl < 2; ++hl)
#pragma unroll
        for (int mt = 0; mt < 4; ++mt)
#pragma unroll
            for (int n2 = 0; n2 < 2; ++n2)
#pragma unroll
                for (int j = 0; j < 4; ++j) {
                    int row = mt * 16 + g * 4 + j;
                    if (row < 49)
                        sm[13200 + row * 264 + (wv * 2 + hl) * 32 + n2 * 16 + c] = f2bf(oreg[hl][mt][n2][j]);
                }

    // prefetch proj ks=0 weight frags; they complete during the barrier drain
    s16x8 pf[2][4];
#pragma unroll
    for (int n = 0; n < 4; ++n)
        pf[0][n] = *(const s16x8*)&projwC[(((wv * 4 + n) * 8 + 0) * 64 + lane) * 8];
    __syncthreads();

    // ---- Phase E: output projection, double-buffered weight prefetch ----
    f32x4 pacc[4][4];
#pragma unroll
    for (int mt = 0; mt < 4; ++mt)
#pragma unroll
        for (int n = 0; n < 4; ++n) pacc[mt][n] = f32x4{0.f, 0.f, 0.f, 0.f};
#pragma unroll
    for (int ks = 0; ks < 8; ++ks) {
        if (ks < 7) {
#pragma unroll
            for (int n = 0; n < 4; ++n)
                pf[(ks + 1) & 1][n] =
                    *(const s16x8*)&projwC[(((wv * 4 + n) * 8 + (ks + 1)) * 64 + lane) * 8];
        }
        s16x8 ao[4];
#pragma unroll
        for (int mt = 0; mt < 4; ++mt) {
            int row = mt * 16 + c; row = row > 48 ? 48 : row;
            ao[mt] = *(const s16x8*)&sm[13200 + row * 264 + ks * 32 + g * 8];
        }
#pragma unroll
        for (int n = 0; n < 4; ++n)
#pragma unroll
            for (int mt = 0; mt < 4; ++mt)
                pacc[mt][n] = __builtin_amdgcn_mfma_f32_16x16x32_bf16(ao[mt], pf[ks & 1][n], pacc[mt][n], 0, 0, 0);
    }
    float* ob = out + (size_t)b * 12544;
#pragma unroll
    for (int n = 0; n < 4; ++n) {
        int col = (wv * 4 + n) * 16 + c;
        float pb = proj_b[col];
#pragma unroll
        for (int mt = 0; mt < 4; ++mt)
#pragma unroll
            for (int j = 0; j < 4; ++j) {
                int row = mt * 16 + g * 4 + j;
                if (row < 49) ob[row * 256 + col] = pacc[mt][n][j] + pb;
            }
    }
}

extern "C" void kernel_launch(void* const* d_in, const int* in_sizes, int n_in,
                              void* d_out, int out_size, void* d_ws, size_t ws_size,
                              hipStream_t stream) {
    const float* x          = (const float*)d_in[0];
    const float* mask       = (const float*)d_in[1];
    const float* qkv_w      = (const float*)d_in[2];
    const float* qkv_b      = (const float*)d_in[3];
    const float* bias_table = (const float*)d_in[4];
    const float* proj_w     = (const float*)d_in[5];
    const float* proj_b     = (const float*)d_in[6];
    const int*   rel_index  = (const int*)d_in[7];

    u16* qkvwC  = (u16*)d_ws;
    u16* projwC = (u16*)((char*)d_ws + WS_PROJW);
    u16* bmC    = (u16*)((char*)d_ws + WS_BMC);

    prep<<<8192, 256, 0, stream>>>(qkv_w, proj_w, bias_table, rel_index, mask,
                                   qkvwC, projwC, bmC);
    swin_attn<<<2048, 256, 0, stream>>>(x, qkv_b, proj_b, qkvwC, projwC, bmC,
                                        (float*)d_out);
}

// Round 9
// 148.098 us; speedup vs baseline: 1.8216x; 1.0835x over previous
//
#include <hip/hip_runtime.h>

typedef float f32x4 __attribute__((ext_vector_type(4)));
typedef short s16x8 __attribute__((ext_vector_type(8)));
typedef unsigned int u32x4 __attribute__((ext_vector_type(4)));
typedef unsigned short u16;
typedef unsigned int u32;

#define QK_SCALE 0.17677669529663687f  // 32^-0.5

__device__ __forceinline__ u16 f2bf(float f) {
    unsigned u = __builtin_bit_cast(unsigned, f);
    u = (u + 0x7fffu + ((u >> 16) & 1u)) >> 16;
    return (u16)u;
}
__device__ __forceinline__ u32 pk2(float lo, float hi) {
    return (u32)f2bf(lo) | ((u32)f2bf(hi) << 16);
}

// C-frag(pair) -> operand-frag conversion:
// dst lane (c,g) elem e needs M[t=c][u=8g+e]; src lane (c, 2(g&1)+(e>>2)),
// utile=g>>1, j=e&3.  r0/r1 = packed (j0,j1)/(j2,j3) words per utile.
__device__ __forceinline__ s16x8 frag4(u32 r0u0, u32 r1u0, u32 r0u1, u32 r1u1,
                                       int aA, int aB, bool lo) {
    u32x4 w;
    u32 a, bq;
    a  = (u32)__builtin_amdgcn_ds_bpermute(aA, (int)r0u0);
    bq = (u32)__builtin_amdgcn_ds_bpermute(aA, (int)r0u1);
    w[0] = lo ? a : bq;
    a  = (u32)__builtin_amdgcn_ds_bpermute(aA, (int)r1u0);
    bq = (u32)__builtin_amdgcn_ds_bpermute(aA, (int)r1u1);
    w[1] = lo ? a : bq;
    a  = (u32)__builtin_amdgcn_ds_bpermute(aB, (int)r0u0);
    bq = (u32)__builtin_amdgcn_ds_bpermute(aB, (int)r0u1);
    w[2] = lo ? a : bq;
    a  = (u32)__builtin_amdgcn_ds_bpermute(aB, (int)r1u0);
    bq = (u32)__builtin_amdgcn_ds_bpermute(aB, (int)r1u1);
    w[3] = lo ? a : bq;
    return __builtin_bit_cast(s16x8, w);
}

// ---- workspace byte offsets ----
// wqkvC2: 196608 bf16 = 393216 B   [h8][f6 = t3*dt2][ks8][lane64][e8]  (A-frags of W for W·X^T)
// projwC:  65536 bf16 = 131072 B   [nt16][ks8][lane64][e8]
// bmC2  : 2097152 bf16 = 4 MB      [wi64][h8][ntQ4][mtK4][lane64][j4]  (bias+mask, St frag order)
#define WS_PROJW 393216
#define WS_BMC   524288

__global__ void prep(const float* __restrict__ qkv_w, const float* __restrict__ proj_w,
                     const float* __restrict__ bias_table, const int* __restrict__ rel_index,
                     const float* __restrict__ mask,
                     u16* __restrict__ wqkvC2, u16* __restrict__ projwC,
                     u16* __restrict__ bmC2) {
    int i = blockIdx.x * 256 + threadIdx.x;
    if (i < 196608) {                       // qkv weights as A-frags of W·X^T
        int e = i & 7, lane = (i >> 3) & 63, ks = (i >> 9) & 7, dt = (i >> 12) & 1;
        int i2 = i >> 13, t = i2 % 3, h = i2 / 3;
        int c = lane & 15, g = lane >> 4;
        wqkvC2[i] = f2bf(qkv_w[(t * 256 + h * 32 + dt * 16 + c) * 256 + ks * 32 + g * 8 + e]);
    }
    if (i < 65536) {                        // proj weights -> fragment order
        int e = i & 7, lane = (i >> 3) & 63, ks = (i >> 9) & 7, nt = (i >> 12) & 15;
        int c = lane & 15, g = lane >> 4;
        projwC[i] = f2bf(proj_w[(nt * 16 + c) * 256 + ks * 32 + g * 8 + e]);
    }
    {                                       // merged bias+mask, bf16, St C-frag order
        int j = i & 3, lane = (i >> 2) & 63, mtK = (i >> 8) & 3, ntQ = (i >> 10) & 3;
        int h = (i >> 12) & 7, wi = i >> 15;
        int c = lane & 15, g = lane >> 4;
        int q = ntQ * 16 + c, k = mtK * 16 + g * 4 + j;
        float v;
        if (k < 49) v = (q < 49) ? bias_table[rel_index[q * 49 + k] * 8 + h]
                                   + mask[wi * 2401 + q * 49 + k]
                                 : 0.f;
        else        v = -1e30f;             // pad-column mask folded in
        bmC2[i] = f2bf(v);
    }
}

// ---- LDS (u16 offsets), total 22152 u16 = 44,304 B ----
// XS  : [0, 12936)  49 rows x 264  (x window, bf16)
// VT  : 12936 + wv*2304, [d32][tok72-pad] per wave
// OUTS: [0, 12936)  overlaps XS after barrier
__global__ __launch_bounds__(256, 2)
void swin_attn(const float* __restrict__ x,
               const float* __restrict__ qkv_b,
               const float* __restrict__ proj_b,
               const u16* __restrict__ wqkvC2,
               const u16* __restrict__ projwC,
               const u16* __restrict__ bmC2,
               float* __restrict__ out) {
    __shared__ __align__(16) u16 sm[22152];
    const int b = blockIdx.x, tid = threadIdx.x;
    const int wv = tid >> 6, lane = tid & 63, g = lane >> 4, c = lane & 15;
    const int wi = b & 63;
    const int VTb = 12936 + wv * 2304;
    const float* xw = x + (size_t)b * 12544;

    // stage x window (bf16), rows 0..48
    for (int i = tid; i < 49 * 64; i += 256) {
        int row = i >> 6, q4 = i & 63;
        float4 v = ((const float4*)xw)[i];
        ushort4 s;
        s.x = f2bf(v.x); s.y = f2bf(v.y); s.z = f2bf(v.z); s.w = f2bf(v.w);
        *(ushort4*)&sm[row * 264 + q4 * 4] = s;
    }
    __syncthreads();

    const int addrA = ((lane & 15) + ((lane & 16) << 1)) << 2;  // src lane c+32*(g&1)
    const int addrB = addrA + 64;                               // +16 lanes
    const bool lo = lane < 32;                                  // utile = g>>1
    const s16x8 zfrag = {0, 0, 0, 0, 0, 0, 0, 0};

    u32 opk[2][4][2][2];

#pragma unroll
    for (int hl = 0; hl < 2; ++hl) {
        const int h = wv * 2 + hl;

        // ---- QKV as W·X^T: acc[f = t*2+dt][tt], A = W-frag (dbuf), B = X-frag ----
        f32x4 acc[6][4];
#pragma unroll
        for (int f = 0; f < 6; ++f)
#pragma unroll
            for (int tt = 0; tt < 4; ++tt) acc[f][tt] = f32x4{0.f, 0.f, 0.f, 0.f};

        s16x8 wf[2][6];
#pragma unroll
        for (int f = 0; f < 6; ++f)
            wf[0][f] = *(const s16x8*)&wqkvC2[(((h * 6 + f) * 8 + 0) * 64 + lane) * 8];
#pragma unroll
        for (int ks = 0; ks < 8; ++ks) {
            if (ks < 7) {
#pragma unroll
                for (int f = 0; f < 6; ++f)
                    wf[(ks + 1) & 1][f] =
                        *(const s16x8*)&wqkvC2[(((h * 6 + f) * 8 + (ks + 1)) * 64 + lane) * 8];
            }
            s16x8 Xf[4];
#pragma unroll
            for (int tt = 0; tt < 4; ++tt)
                Xf[tt] = *(const s16x8*)&sm[(tt * 16 + c) * 264 + ks * 32 + g * 8];
            if (c > 0) Xf[3] = zfrag;      // tokens 49..63 zero
#pragma unroll
            for (int f = 0; f < 6; ++f)
#pragma unroll
                for (int tt = 0; tt < 4; ++tt)
                    acc[f][tt] = __builtin_amdgcn_mfma_f32_16x16x32_bf16(wf[ks & 1][f], Xf[tt], acc[f][tt], 0, 0, 0);
        }

        // ---- bias, pack Qt/Kt to regs; Vt -> VT LDS ----
        u32 qp[4][2][2], kp[4][2][2];
#pragma unroll
        for (int f = 0; f < 6; ++f) {
            int t = f >> 1, dt = f & 1;
            f32x4 bv = *(const f32x4*)&qkv_b[t * 256 + h * 32 + dt * 16 + g * 4];
#pragma unroll
            for (int tt = 0; tt < 4; ++tt) {
                float v0 = acc[f][tt][0] + bv[0];
                float v1 = acc[f][tt][1] + bv[1];
                float v2 = acc[f][tt][2] + bv[2];
                float v3 = acc[f][tt][3] + bv[3];
                if (t == 0) {
                    qp[tt][dt][0] = pk2(v0 * QK_SCALE, v1 * QK_SCALE);
                    qp[tt][dt][1] = pk2(v2 * QK_SCALE, v3 * QK_SCALE);
                } else if (t == 1) {
                    kp[tt][dt][0] = pk2(v0, v1);
                    kp[tt][dt][1] = pk2(v2, v3);
                } else {
                    sm[VTb + (dt * 16 + g * 4 + 0) * 72 + tt * 16 + c] = f2bf(v0);
                    sm[VTb + (dt * 16 + g * 4 + 1) * 72 + tt * 16 + c] = f2bf(v1);
                    sm[VTb + (dt * 16 + g * 4 + 2) * 72 + tt * 16 + c] = f2bf(v2);
                    sm[VTb + (dt * 16 + g * 4 + 3) * 72 + tt * 16 + c] = f2bf(v3);
                }
            }
        }

        // ---- issue bias/mask loads early (hide L2 latency under frag4 + MFMA) ----
        u32 bm0[4][4], bm1[4][4];
#pragma unroll
        for (int ntQ = 0; ntQ < 4; ++ntQ)
#pragma unroll
            for (int mtK = 0; mtK < 4; ++mtK) {
                const u32* bp = (const u32*)&bmC2[((((wi * 8 + h) * 4 + ntQ) * 4 + mtK) * 64 + lane) * 4];
                bm0[ntQ][mtK] = bp[0];
                bm1[ntQ][mtK] = bp[1];
            }

        // ---- operand frags for St = K·Q^T (both lane&15 = token) ----
        s16x8 Qf[4], Kf[4];
#pragma unroll
        for (int nt = 0; nt < 4; ++nt)
            Qf[nt] = frag4(qp[nt][0][0], qp[nt][0][1], qp[nt][1][0], qp[nt][1][1], addrA, addrB, lo);
#pragma unroll
        for (int mt = 0; mt < 4; ++mt)
            Kf[mt] = frag4(kp[mt][0][0], kp[mt][0][1], kp[mt][1][0], kp[mt][1][1], addrA, addrB, lo);

        // ---- St (16 MFMA) + bias/mask, lane-local softmax (q = c, k = mtK*16+g*4+j) ----
        f32x4 lv[4][4];
#pragma unroll
        for (int mtK = 0; mtK < 4; ++mtK)
#pragma unroll
            for (int ntQ = 0; ntQ < 4; ++ntQ) {
                f32x4 z = {0.f, 0.f, 0.f, 0.f};
                lv[mtK][ntQ] = __builtin_amdgcn_mfma_f32_16x16x32_bf16(Kf[mtK], Qf[ntQ], z, 0, 0, 0);
            }
        float mx[4] = {-1e30f, -1e30f, -1e30f, -1e30f};
#pragma unroll
        for (int ntQ = 0; ntQ < 4; ++ntQ)
#pragma unroll
            for (int mtK = 0; mtK < 4; ++mtK) {
                u32 w0 = bm0[ntQ][mtK], w1 = bm1[ntQ][mtK];
                float b0 = __builtin_bit_cast(float, w0 << 16);
                float b1 = __builtin_bit_cast(float, w0 & 0xffff0000u);
                float b2 = __builtin_bit_cast(float, w1 << 16);
                float b3 = __builtin_bit_cast(float, w1 & 0xffff0000u);
                float v0 = lv[mtK][ntQ][0] + b0;
                float v1 = lv[mtK][ntQ][1] + b1;
                float v2 = lv[mtK][ntQ][2] + b2;
                float v3 = lv[mtK][ntQ][3] + b3;
                lv[mtK][ntQ][0] = v0; lv[mtK][ntQ][1] = v1;
                lv[mtK][ntQ][2] = v2; lv[mtK][ntQ][3] = v3;
                mx[ntQ] = fmaxf(mx[ntQ], fmaxf(fmaxf(v0, v1), fmaxf(v2, v3)));
            }
#pragma unroll
        for (int ntQ = 0; ntQ < 4; ++ntQ) {
            float m = mx[ntQ];
            m = fmaxf(m, __shfl_xor(m, 16));
            m = fmaxf(m, __shfl_xor(m, 32));
            mx[ntQ] = m;
        }
        float sums[4] = {0.f, 0.f, 0.f, 0.f};
#pragma unroll
        for (int ntQ = 0; ntQ < 4; ++ntQ)
#pragma unroll
            for (int mtK = 0; mtK < 4; ++mtK)
#pragma unroll
                for (int j = 0; j < 4; ++j) {
                    float e = __expf(lv[mtK][ntQ][j] - mx[ntQ]);
                    lv[mtK][ntQ][j] = e;
                    sums[ntQ] += e;
                }
#pragma unroll
        for (int ntQ = 0; ntQ < 4; ++ntQ) {
            float s = sums[ntQ];
            s += __shfl_xor(s, 16);
            s += __shfl_xor(s, 32);
            sums[ntQ] = 1.0f / s;
        }
        // normalized P packed (q = c, so inv-sum is lane-local)
        u32 pp[4][4][2];
#pragma unroll
        for (int mtK = 0; mtK < 4; ++mtK)
#pragma unroll
            for (int ntQ = 0; ntQ < 4; ++ntQ) {
                float is = sums[ntQ];
                pp[mtK][ntQ][0] = pk2(lv[mtK][ntQ][0] * is, lv[mtK][ntQ][1] * is);
                pp[mtK][ntQ][1] = pk2(lv[mtK][ntQ][2] * is, lv[mtK][ntQ][3] * is);
            }

        // ---- PV: A = P-frag (bpermute), B = VT from LDS ----
#pragma unroll
        for (int mtQ = 0; mtQ < 4; ++mtQ) {
            f32x4 o[2] = {{0.f, 0.f, 0.f, 0.f}, {0.f, 0.f, 0.f, 0.f}};
#pragma unroll
            for (int ks2 = 0; ks2 < 2; ++ks2) {
                s16x8 Pf = frag4(pp[2 * ks2][mtQ][0], pp[2 * ks2][mtQ][1],
                                 pp[2 * ks2 + 1][mtQ][0], pp[2 * ks2 + 1][mtQ][1], addrA, addrB, lo);
#pragma unroll
                for (int ndt = 0; ndt < 2; ++ndt) {
                    s16x8 Vf = *(const s16x8*)&sm[VTb + (ndt * 16 + c) * 72 + ks2 * 32 + g * 8];
                    o[ndt] = __builtin_amdgcn_mfma_f32_16x16x32_bf16(Pf, Vf, o[ndt], 0, 0, 0);
                }
            }
#pragma unroll
            for (int ndt = 0; ndt < 2; ++ndt) {
                opk[hl][mtQ][ndt][0] = pk2(o[ndt][0], o[ndt][1]);
                opk[hl][mtQ][ndt][1] = pk2(o[ndt][2], o[ndt][3]);
            }
        }
    }

    __syncthreads();   // all waves done with XS reads / wave scratch
    // stage head outputs into OUTS (overlaps XS)
#pragma unroll
    for (int hl = 0; hl < 2; ++hl)
#pragma unroll
        for (int mt = 0; mt < 4; ++mt)
#pragma unroll
            for (int n2 = 0; n2 < 2; ++n2)
#pragma unroll
                for (int jj = 0; jj < 2; ++jj) {
                    u32 w = opk[hl][mt][n2][jj];
                    int row = mt * 16 + g * 4 + jj * 2;
                    int colb = (wv * 2 + hl) * 32 + n2 * 16 + c;
                    if (row < 49)     sm[row * 264 + colb] = (u16)(w & 0xffffu);
                    if (row + 1 < 49) sm[(row + 1) * 264 + colb] = (u16)(w >> 16);
                }

    // prefetch proj ks=0 weight frags; they complete during the barrier drain
    s16x8 pf[2][4];
#pragma unroll
    for (int n = 0; n < 4; ++n)
        pf[0][n] = *(const s16x8*)&projwC[(((wv * 4 + n) * 8 + 0) * 64 + lane) * 8];
    __syncthreads();

    // ---- output projection: wave wv covers cols [wv*64, wv*64+64), dbuf weights ----
    f32x4 pacc[4][4];
#pragma unroll
    for (int mt = 0; mt < 4; ++mt)
#pragma unroll
        for (int n = 0; n < 4; ++n) pacc[mt][n] = f32x4{0.f, 0.f, 0.f, 0.f};
#pragma unroll
    for (int ks = 0; ks < 8; ++ks) {
        if (ks < 7) {
#pragma unroll
            for (int n = 0; n < 4; ++n)
                pf[(ks + 1) & 1][n] =
                    *(const s16x8*)&projwC[(((wv * 4 + n) * 8 + (ks + 1)) * 64 + lane) * 8];
        }
        s16x8 ao[4];
#pragma unroll
        for (int mt = 0; mt < 4; ++mt) {
            int row = mt * 16 + c; row = row > 48 ? 48 : row;
            ao[mt] = *(const s16x8*)&sm[row * 264 + ks * 32 + g * 8];
        }
#pragma unroll
        for (int n = 0; n < 4; ++n)
#pragma unroll
            for (int mt = 0; mt < 4; ++mt)
                pacc[mt][n] = __builtin_amdgcn_mfma_f32_16x16x32_bf16(ao[mt], pf[ks & 1][n], pacc[mt][n], 0, 0, 0);
    }
    float* ob = out + (size_t)b * 12544;
#pragma unroll
    for (int n = 0; n < 4; ++n) {
        int col = (wv * 4 + n) * 16 + c;
        float pb = proj_b[col];
#pragma unroll
        for (int mt = 0; mt < 4; ++mt)
#pragma unroll
            for (int j = 0; j < 4; ++j) {
                int row = mt * 16 + g * 4 + j;
                if (row < 49) ob[row * 256 + col] = pacc[mt][n][j] + pb;
            }
    }
}

extern "C" void kernel_launch(void* const* d_in, const int* in_sizes, int n_in,
                              void* d_out, int out_size, void* d_ws, size_t ws_size,
                              hipStream_t stream) {
    const float* x          = (const float*)d_in[0];
    const float* mask       = (const float*)d_in[1];
    const float* qkv_w      = (const float*)d_in[2];
    const float* qkv_b      = (const float*)d_in[3];
    const float* bias_table = (const float*)d_in[4];
    const float* proj_w     = (const float*)d_in[5];
    const float* proj_b     = (const float*)d_in[6];
    const int*   rel_index  = (const int*)d_in[7];

    u16* wqkvC2 = (u16*)d_ws;
    u16* projwC = (u16*)((char*)d_ws + WS_PROJW);
    u16* bmC2   = (u16*)((char*)d_ws + WS_BMC);

    prep<<<8192, 256, 0, stream>>>(qkv_w, proj_w, bias_table, rel_index, mask,
                                   wqkvC2, projwC, bmC2);
    swin_attn<<<2048, 256, 0, stream>>>(x, qkv_b, proj_b, wqkvC2, projwC, bmC2,
                                        (float*)d_out);
}